// Round 1
// baseline (238.493 us; speedup 1.0000x reference)
//
#include <hip/hip_runtime.h>
#include <cstdint>
#include <cstddef>

// Problem constants
#define MB_   4096
#define NK_   8
#define DM_   1024
#define DT_   128
// Derived: A-rows of big GEMM = 4096, K = 1024, N = 8192

typedef __bf16 bf16;
typedef __bf16 bf16x8 __attribute__((ext_vector_type(8)));
typedef __bf16 bf16x4 __attribute__((ext_vector_type(4)));
typedef float  f32x4  __attribute__((ext_vector_type(4)));

__device__ __forceinline__ void gload_lds16(const void* g, void* l) {
  __builtin_amdgcn_global_load_lds(
      (__attribute__((address_space(1))) void*)g,
      (__attribute__((address_space(3))) void*)l,
      16, 0, 0);
}

// ---------------------------------------------------------------------------
// prep: proj_w f32 [8192][1024] -> bf16
__global__ void prep_pw_kernel(const float* __restrict__ pw, bf16* __restrict__ pwb) {
  size_t i = ((size_t)blockIdx.x * 256 + threadIdx.x) * 4;
  float4 f = *(const float4*)&pw[i];
  bf16x4 o = { (bf16)f.x, (bf16)f.y, (bf16)f.z, (bf16)f.w };
  *(bf16x4*)&pwb[i] = o;
}

// prep: w_vs [8][1024][128] f32 -> WvT [8][128][1024] bf16 (transpose d<->t)
__global__ void prep_wvt_kernel(const float* __restrict__ wvs, bf16* __restrict__ wvt) {
  int o = blockIdx.x * 256 + threadIdx.x;   // 1048576 outputs
  int d = o & 1023;
  int t = (o >> 10) & 127;
  int n = o >> 17;
  wvt[o] = (bf16)wvs[(size_t)n * 131072 + (size_t)d * 128 + t];
}

// attns output: all ones
__global__ void fill_attns_kernel(float* __restrict__ out) {
  out[(size_t)33554432 + blockIdx.x * 256 + threadIdx.x] = 1.0f;
}

// ---------------------------------------------------------------------------
// GEMM1: for n in [0,8): v_s[n] = V_n[4096x1024](f32) @ WvT[n][128x1024]^T (bf16)
// Output scattered into A2[m][c] bf16 (the torch raw-reshape layout).
// Tile 128x128, BK=32, 4 waves each 64x64 via 4x4 frags of 16x16x32.
__global__ __launch_bounds__(256, 2) void gemm1_kernel(
    const float* __restrict__ vflat, const bf16* __restrict__ WvT,
    bf16* __restrict__ A2)
{
  __shared__ __align__(16) bf16 As[128 * 32];
  __shared__ __align__(16) bf16 Bs[128 * 32];
  const int tid  = threadIdx.x;
  const int wave = tid >> 6, lane = tid & 63;
  const int wm = wave >> 1, wn = wave & 1;
  const int n  = blockIdx.y;          // batch 0..7
  const int b0 = blockIdx.x * 128;    // row tile

  const float* ag = vflat + ((size_t)(n * MB_ + b0 + (tid >> 1))) * 1024 + (tid & 1) * 16;
  const bf16*  bg = WvT + (size_t)n * 128 * 1024 + (size_t)(tid >> 2) * 1024 + (tid & 3) * 8;
  char* bsb = (char*)Bs + wave * 1024;

  f32x4 acc[4][4] = {};
  const int krow = lane & 15;
  const int kcol = (lane >> 4) * 8;
  const int a_off = (tid >> 1) * 32 + (tid & 1) * 16;

  for (int kt = 0; kt < 32; ++kt) {
    // B -> LDS async
    const bf16* bptr = bg + kt * 32;
    gload_lds16(bptr,              bsb);
    gload_lds16(bptr + 64 * 1024,  bsb + 4096);
    // A: f32 regs -> bf16 -> LDS
    const float* aptr = ag + kt * 32;
    float4 f0 = *(const float4*)(aptr + 0);
    float4 f1 = *(const float4*)(aptr + 4);
    float4 f2 = *(const float4*)(aptr + 8);
    float4 f3 = *(const float4*)(aptr + 12);
    bf16x8 h0 = { (bf16)f0.x, (bf16)f0.y, (bf16)f0.z, (bf16)f0.w,
                  (bf16)f1.x, (bf16)f1.y, (bf16)f1.z, (bf16)f1.w };
    bf16x8 h1 = { (bf16)f2.x, (bf16)f2.y, (bf16)f2.z, (bf16)f2.w,
                  (bf16)f3.x, (bf16)f3.y, (bf16)f3.z, (bf16)f3.w };
    *(bf16x8*)&As[a_off]     = h0;
    *(bf16x8*)&As[a_off + 8] = h1;
    __syncthreads();

    bf16x8 af[4], bfr[4];
    #pragma unroll
    for (int i = 0; i < 4; ++i)
      af[i] = *(const bf16x8*)&As[(wm * 64 + i * 16 + krow) * 32 + kcol];
    #pragma unroll
    for (int j = 0; j < 4; ++j)
      bfr[j] = *(const bf16x8*)&Bs[(wn * 64 + j * 16 + krow) * 32 + kcol];
    #pragma unroll
    for (int i = 0; i < 4; ++i)
      #pragma unroll
      for (int j = 0; j < 4; ++j)
        acc[i][j] = __builtin_amdgcn_mfma_f32_16x16x32_bf16(af[i], bfr[j], acc[i][j], 0, 0, 0);
    __syncthreads();
  }

  // epilogue: scatter v_s[n][b][t] -> A2[n*512 + (b>>3)][(b&7)*128 + t]  (bf16)
  #pragma unroll
  for (int i = 0; i < 4; ++i) {
    #pragma unroll
    for (int j = 0; j < 4; ++j) {
      int t = wn * 64 + j * 16 + (lane & 15);
      #pragma unroll
      for (int r = 0; r < 4; ++r) {
        int b = b0 + wm * 64 + i * 16 + (lane >> 4) * 4 + r;
        size_t off = ((size_t)(n * 512 + (b >> 3))) * 1024 + (size_t)(b & 7) * 128 + t;
        A2[off] = (bf16)acc[i][j][r];
      }
    }
  }
}

// ---------------------------------------------------------------------------
// GEMM2: z[4096][8192] = A2[4096][1024](bf16) @ PW[8192][1024]^T (bf16)
//        + v(as [4096][8192]) + proj_b ; write f32 into d_out (z scratch)
__global__ __launch_bounds__(256, 2) void gemm2_kernel(
    const bf16* __restrict__ A2, const bf16* __restrict__ PW,
    const float* __restrict__ vres, const float* __restrict__ pb,
    float* __restrict__ zout)
{
  __shared__ __align__(16) bf16 As[128 * 32];
  __shared__ __align__(16) bf16 Bs[128 * 32];
  const int tid  = threadIdx.x;
  const int wave = tid >> 6, lane = tid & 63;
  const int wm = wave >> 1, wn = wave & 1;
  const int m0 = blockIdx.y * 128;   // 0..31
  const int n0 = blockIdx.x * 128;   // 0..63

  const bf16* ag = A2 + (size_t)(m0 + (tid >> 2)) * 1024 + (tid & 3) * 8;
  const bf16* bg = PW + (size_t)(n0 + (tid >> 2)) * 1024 + (tid & 3) * 8;
  char* asb = (char*)As + wave * 1024;
  char* bsb = (char*)Bs + wave * 1024;

  f32x4 acc[4][4] = {};
  const int krow = lane & 15;
  const int kcol = (lane >> 4) * 8;

  for (int kt = 0; kt < 32; ++kt) {
    const bf16* a0 = ag + kt * 32;
    const bf16* b0 = bg + kt * 32;
    gload_lds16(a0,             asb);
    gload_lds16(a0 + 64 * 1024, asb + 4096);
    gload_lds16(b0,             bsb);
    gload_lds16(b0 + 64 * 1024, bsb + 4096);
    __syncthreads();

    bf16x8 af[4], bfr[4];
    #pragma unroll
    for (int i = 0; i < 4; ++i)
      af[i] = *(const bf16x8*)&As[(wm * 64 + i * 16 + krow) * 32 + kcol];
    #pragma unroll
    for (int j = 0; j < 4; ++j)
      bfr[j] = *(const bf16x8*)&Bs[(wn * 64 + j * 16 + krow) * 32 + kcol];
    #pragma unroll
    for (int i = 0; i < 4; ++i)
      #pragma unroll
      for (int j = 0; j < 4; ++j)
        acc[i][j] = __builtin_amdgcn_mfma_f32_16x16x32_bf16(af[i], bfr[j], acc[i][j], 0, 0, 0);
    __syncthreads();
  }

  #pragma unroll
  for (int i = 0; i < 4; ++i) {
    #pragma unroll
    for (int j = 0; j < 4; ++j) {
      int nn = n0 + wn * 64 + j * 16 + (lane & 15);
      float pbn = pb[nn];
      #pragma unroll
      for (int r = 0; r < 4; ++r) {
        int mm = m0 + wm * 64 + i * 16 + (lane >> 4) * 4 + r;
        size_t off = (size_t)mm * 8192 + nn;
        zout[off] = acc[i][j][r] + vres[off] + pbn;
      }
    }
  }
}

// ---------------------------------------------------------------------------
// LayerNorm (ddof=1, eps OUTSIDE sqrt) over 1024-wide rows, in-place in d_out.
__global__ __launch_bounds__(256) void ln_kernel(
    float* __restrict__ z, const float* __restrict__ gamma, const float* __restrict__ beta)
{
  __shared__ float red[16];
  const int row = blockIdx.x;          // 0..32767
  const int tid = threadIdx.x;
  float* zr = z + (size_t)row * 1024;
  float4 x = *(const float4*)&zr[tid * 4];
  float s  = x.x + x.y + x.z + x.w;
  float ss = x.x * x.x + x.y * x.y + x.z * x.z + x.w * x.w;
  #pragma unroll
  for (int m = 32; m >= 1; m >>= 1) {
    s  += __shfl_xor(s,  m, 64);
    ss += __shfl_xor(ss, m, 64);
  }
  const int wave = tid >> 6, lane = tid & 63;
  if (lane == 0) { red[wave] = s; red[wave + 8] = ss; }
  __syncthreads();
  float S  = red[0] + red[1] + red[2] + red[3];
  float SS = red[8] + red[9] + red[10] + red[11];
  float mu  = S * (1.0f / 1024.0f);
  float var = (SS - 1024.0f * mu * mu) * (1.0f / 1023.0f);
  var = var < 0.0f ? 0.0f : var;
  float rs = 1.0f / (sqrtf(var) + 1e-3f);
  float4 g  = *(const float4*)&gamma[tid * 4];
  float4 be = *(const float4*)&beta[tid * 4];
  float4 y;
  y.x = (x.x - mu) * rs * g.x + be.x;
  y.y = (x.y - mu) * rs * g.y + be.y;
  y.z = (x.z - mu) * rs * g.z + be.z;
  y.w = (x.w - mu) * rs * g.w + be.w;
  *(float4*)&zr[tid * 4] = y;
}

// ---------------------------------------------------------------------------
extern "C" void kernel_launch(void* const* d_in, const int* in_sizes, int n_in,
                              void* d_out, int out_size, void* d_ws, size_t ws_size,
                              hipStream_t stream) {
  // inputs: 0:q 1:k 2:v 3:w_qs 4:w_ks 5:w_vs 6:proj_w 7:proj_b 8:gamma 9:beta
  const float* v     = (const float*)d_in[2];
  const float* wvs   = (const float*)d_in[5];
  const float* pw    = (const float*)d_in[6];
  const float* pb    = (const float*)d_in[7];
  const float* gamma = (const float*)d_in[8];
  const float* beta  = (const float*)d_in[9];
  float* out = (float*)d_out;

  // workspace layout (bf16): PW 16MB | WvT 2MB | A2 8MB  (~26MB total)
  bf16* PWb = (bf16*)d_ws;
  bf16* WvT = (bf16*)((char*)d_ws + (size_t)16777216);
  bf16* A2  = (bf16*)((char*)d_ws + (size_t)16777216 + 2097152);

  hipLaunchKernelGGL(prep_pw_kernel,  dim3(8192), dim3(256), 0, stream, pw, PWb);
  hipLaunchKernelGGL(prep_wvt_kernel, dim3(4096), dim3(256), 0, stream, wvs, WvT);
  hipLaunchKernelGGL(fill_attns_kernel, dim3(128), dim3(256), 0, stream, out);
  hipLaunchKernelGGL(gemm1_kernel, dim3(32, 8),  dim3(256), 0, stream, v, WvT, A2);
  hipLaunchKernelGGL(gemm2_kernel, dim3(64, 32), dim3(256), 0, stream, A2, PWb, v, pb, out);
  hipLaunchKernelGGL(ln_kernel,    dim3(32768),  dim3(256), 0, stream, out, gamma, beta);
}

// Round 2
// 204.191 us; speedup vs baseline: 1.1680x; 1.1680x over previous
//
#include <hip/hip_runtime.h>
#include <cstdint>
#include <cstddef>

#define MB_   4096
#define NK_   8
#define DM_   1024
#define DT_   128

typedef __bf16 bf16;
typedef __bf16 bf16x8 __attribute__((ext_vector_type(8)));
typedef __bf16 bf16x4 __attribute__((ext_vector_type(4)));
typedef float  f32x4  __attribute__((ext_vector_type(4)));

__device__ __forceinline__ void gload_lds16(const void* g, void* l) {
  __builtin_amdgcn_global_load_lds(
      (__attribute__((address_space(1))) void*)g,
      (__attribute__((address_space(3))) void*)l,
      16, 0, 0);
}

// XOR swizzle: logical 16B-chunk c of row r lives at LDS slot c ^ hsw(r).
// hsw(r) = (r ^ (r>>2)) & 3 spreads 8 consecutive rows over all 8 bank-sets.
__device__ __forceinline__ int hsw(int r) { return (r ^ (r >> 2)) & 3; }

// ---------------------------------------------------------------------------
// prep: proj_w f32 [8192][1024] -> bf16
__global__ void prep_pw_kernel(const float* __restrict__ pw, bf16* __restrict__ pwb) {
  size_t i = ((size_t)blockIdx.x * 256 + threadIdx.x) * 4;
  float4 f = *(const float4*)&pw[i];
  bf16x4 o = { (bf16)f.x, (bf16)f.y, (bf16)f.z, (bf16)f.w };
  *(bf16x4*)&pwb[i] = o;
}

// prep: w_vs [8][1024][128] f32 -> WvT [8][128][1024] bf16 (transpose d<->t)
__global__ void prep_wvt_kernel(const float* __restrict__ wvs, bf16* __restrict__ wvt) {
  int o = blockIdx.x * 256 + threadIdx.x;
  int d = o & 1023;
  int t = (o >> 10) & 127;
  int n = o >> 17;
  wvt[o] = (bf16)wvs[(size_t)n * 131072 + (size_t)d * 128 + t];
}

__global__ void fill_attns_kernel(float* __restrict__ out) {
  out[(size_t)33554432 + blockIdx.x * 256 + threadIdx.x] = 1.0f;
}

// ---------------------------------------------------------------------------
// GEMM1: v_s[n] = V_n[4096x1024](f32) @ WvT[n][128x1024]^T -> A2 scatter (bf16)
// Tile 64x128, BK=32, 4 waves each 32x64 (2x4 frags). Swizzled LDS.
__global__ __launch_bounds__(256, 2) void gemm1_kernel(
    const float* __restrict__ vflat, const bf16* __restrict__ WvT,
    bf16* __restrict__ A2)
{
  __shared__ __align__(16) bf16 As[64 * 32];
  __shared__ __align__(16) bf16 Bs[128 * 32];
  const int tid  = threadIdx.x;
  const int wave = tid >> 6, lane = tid & 63;
  const int wm = wave >> 1, wn = wave & 1;
  const int n  = blockIdx.y;
  const int b0 = blockIdx.x * 64;

  const int r  = tid >> 2;                 // 0..63
  const int hr = hsw(r);                   // hsw(r) == hsw(r+64)
  const int cs = (tid & 3) ^ hr;           // swizzled chunk

  // A: thread holds logical chunk (tid&3) of row r -> writes LDS slot cs
  const float* ag = vflat + ((size_t)(n * MB_ + b0 + r)) * 1024 + (tid & 3) * 8;
  bf16* awr = As + r * 32 + cs * 8;
  // B: LDS linear slot (tid&3) must receive logical chunk cs -> source swizzled
  const bf16* bg = WvT + (size_t)n * 131072 + (size_t)r * 1024 + cs * 8;
  char* bsb = (char*)Bs + wave * 1024;

  f32x4 acc[2][4] = {};
  const int krow = lane & 15;
  const int cch  = lane >> 4;
  const int swoff = ((cch ^ hsw(krow)) << 4);  // hsw(wm*32+i*16+krow) == hsw(krow)

  for (int kt = 0; kt < 32; ++kt) {
    const bf16* bptr = bg + kt * 32;
    gload_lds16(bptr,             bsb);
    gload_lds16(bptr + 64 * 1024, bsb + 4096);
    const float* aptr = ag + kt * 32;
    float4 f0 = *(const float4*)(aptr + 0);
    float4 f1 = *(const float4*)(aptr + 4);
    bf16x8 h0 = { (bf16)f0.x, (bf16)f0.y, (bf16)f0.z, (bf16)f0.w,
                  (bf16)f1.x, (bf16)f1.y, (bf16)f1.z, (bf16)f1.w };
    *(bf16x8*)awr = h0;
    __syncthreads();

    bf16x8 af[2], bfr[4];
    #pragma unroll
    for (int i = 0; i < 2; ++i)
      af[i] = *(const bf16x8*)((const char*)As + (wm * 32 + i * 16 + krow) * 64 + swoff);
    #pragma unroll
    for (int j = 0; j < 4; ++j)
      bfr[j] = *(const bf16x8*)((const char*)Bs + (wn * 64 + j * 16 + krow) * 64 + swoff);
    #pragma unroll
    for (int i = 0; i < 2; ++i)
      #pragma unroll
      for (int j = 0; j < 4; ++j)
        acc[i][j] = __builtin_amdgcn_mfma_f32_16x16x32_bf16(af[i], bfr[j], acc[i][j], 0, 0, 0);
    __syncthreads();
  }

  #pragma unroll
  for (int i = 0; i < 2; ++i) {
    #pragma unroll
    for (int j = 0; j < 4; ++j) {
      int t = wn * 64 + j * 16 + (lane & 15);
      #pragma unroll
      for (int rr = 0; rr < 4; ++rr) {
        int b = b0 + wm * 32 + i * 16 + (lane >> 4) * 4 + rr;
        size_t off = ((size_t)(n * 512 + (b >> 3))) * 1024 + (size_t)(b & 7) * 128 + t;
        A2[off] = (bf16)acc[i][j][rr];
      }
    }
  }
}

// ---------------------------------------------------------------------------
// GEMM2: z[4096][8192] = A2 @ PW^T + proj_b  (residual handled in LN)
// ZB: write bf16 to workspace; else f32 to d_out.
template<bool ZB>
__global__ __launch_bounds__(256, 2) void gemm2_kernel(
    const bf16* __restrict__ A2, const bf16* __restrict__ PW,
    const float* __restrict__ pb, void* __restrict__ zoutp)
{
  __shared__ __align__(16) bf16 As[128 * 32];
  __shared__ __align__(16) bf16 Bs[128 * 32];
  const int tid  = threadIdx.x;
  const int wave = tid >> 6, lane = tid & 63;
  const int wm = wave >> 1, wn = wave & 1;
  const int m0 = blockIdx.y * 128;
  const int n0 = blockIdx.x * 128;

  const int r  = tid >> 2;
  const int hr = hsw(r);
  const int cs = (tid & 3) ^ hr;

  const bf16* ag = A2 + (size_t)(m0 + r) * 1024 + cs * 8;
  const bf16* bg = PW + (size_t)(n0 + r) * 1024 + cs * 8;
  char* asb = (char*)As + wave * 1024;
  char* bsb = (char*)Bs + wave * 1024;

  f32x4 acc[4][4] = {};
  const int krow = lane & 15;
  const int cch  = lane >> 4;
  const int swoff = ((cch ^ hsw(krow)) << 4);

  for (int kt = 0; kt < 32; ++kt) {
    const bf16* a0 = ag + kt * 32;
    const bf16* b0 = bg + kt * 32;
    gload_lds16(a0,             asb);
    gload_lds16(a0 + 64 * 1024, asb + 4096);
    gload_lds16(b0,             bsb);
    gload_lds16(b0 + 64 * 1024, bsb + 4096);
    __syncthreads();

    bf16x8 af[4], bfr[4];
    #pragma unroll
    for (int i = 0; i < 4; ++i)
      af[i] = *(const bf16x8*)((const char*)As + (wm * 64 + i * 16 + krow) * 64 + swoff);
    #pragma unroll
    for (int j = 0; j < 4; ++j)
      bfr[j] = *(const bf16x8*)((const char*)Bs + (wn * 64 + j * 16 + krow) * 64 + swoff);
    #pragma unroll
    for (int i = 0; i < 4; ++i)
      #pragma unroll
      for (int j = 0; j < 4; ++j)
        acc[i][j] = __builtin_amdgcn_mfma_f32_16x16x32_bf16(af[i], bfr[j], acc[i][j], 0, 0, 0);
    __syncthreads();
  }

  #pragma unroll
  for (int i = 0; i < 4; ++i) {
    #pragma unroll
    for (int j = 0; j < 4; ++j) {
      int nn = n0 + wn * 64 + j * 16 + (lane & 15);
      float pbn = pb[nn];
      #pragma unroll
      for (int rr = 0; rr < 4; ++rr) {
        int mm = m0 + wm * 64 + i * 16 + (lane >> 4) * 4 + rr;
        size_t off = (size_t)mm * 8192 + nn;
        float val = acc[i][j][rr] + pbn;
        if (ZB) ((bf16*)zoutp)[off] = (bf16)val;
        else    ((float*)zoutp)[off] = val;
      }
    }
  }
}

// ---------------------------------------------------------------------------
// LN over 1024-wide rows: x = z + v(residual); ddof=1, eps outside sqrt.
template<bool ZB>
__global__ __launch_bounds__(256) void ln_kernel(
    const void* zin, const float* __restrict__ vres,
    const float* __restrict__ gamma, const float* __restrict__ beta,
    float* outp)
{
  __shared__ float red[16];
  const int row = blockIdx.x;
  const int tid = threadIdx.x;
  const size_t base = (size_t)row * 1024 + tid * 4;

  float4 rv = *(const float4*)&vres[base];
  float4 x;
  if (ZB) {
    bf16x4 zb4 = *(const bf16x4*)((const bf16*)zin + base);
    x.x = (float)zb4[0] + rv.x; x.y = (float)zb4[1] + rv.y;
    x.z = (float)zb4[2] + rv.z; x.w = (float)zb4[3] + rv.w;
  } else {
    float4 zf = *(const float4*)((const float*)zin + base);
    x.x = zf.x + rv.x; x.y = zf.y + rv.y; x.z = zf.z + rv.z; x.w = zf.w + rv.w;
  }

  float s  = x.x + x.y + x.z + x.w;
  float ss = x.x * x.x + x.y * x.y + x.z * x.z + x.w * x.w;
  #pragma unroll
  for (int m = 32; m >= 1; m >>= 1) {
    s  += __shfl_xor(s,  m, 64);
    ss += __shfl_xor(ss, m, 64);
  }
  const int wave = tid >> 6, lane = tid & 63;
  if (lane == 0) { red[wave] = s; red[wave + 8] = ss; }
  __syncthreads();
  float S  = red[0] + red[1] + red[2] + red[3];
  float SS = red[8] + red[9] + red[10] + red[11];
  float mu  = S * (1.0f / 1024.0f);
  float var = (SS - 1024.0f * mu * mu) * (1.0f / 1023.0f);
  var = var < 0.0f ? 0.0f : var;
  float rs = 1.0f / (sqrtf(var) + 1e-3f);
  float4 g  = *(const float4*)&gamma[tid * 4];
  float4 be = *(const float4*)&beta[tid * 4];
  float4 y;
  y.x = (x.x - mu) * rs * g.x + be.x;
  y.y = (x.y - mu) * rs * g.y + be.y;
  y.z = (x.z - mu) * rs * g.z + be.z;
  y.w = (x.w - mu) * rs * g.w + be.w;
  *(float4*)&outp[base] = y;
}

// ---------------------------------------------------------------------------
extern "C" void kernel_launch(void* const* d_in, const int* in_sizes, int n_in,
                              void* d_out, int out_size, void* d_ws, size_t ws_size,
                              hipStream_t stream) {
  const float* v     = (const float*)d_in[2];
  const float* wvs   = (const float*)d_in[5];
  const float* pw    = (const float*)d_in[6];
  const float* pb    = (const float*)d_in[7];
  const float* gamma = (const float*)d_in[8];
  const float* beta  = (const float*)d_in[9];
  float* out = (float*)d_out;

  // ws layout (bytes): PW bf16 16M | WvT bf16 2M | A2 bf16 8M | zg bf16 64M
  const size_t OFF_WVT = 16777216;
  const size_t OFF_A2  = OFF_WVT + 2097152;
  const size_t OFF_ZG  = OFF_A2 + 8388608;
  const size_t NEED_ZB = OFF_ZG + 67108864;

  bf16* PWb = (bf16*)d_ws;
  bf16* WvT = (bf16*)((char*)d_ws + OFF_WVT);
  bf16* A2  = (bf16*)((char*)d_ws + OFF_A2);
  const bool zb = (ws_size >= NEED_ZB);
  void* zbuf = zb ? (void*)((char*)d_ws + OFF_ZG) : (void*)out;

  hipLaunchKernelGGL(prep_pw_kernel,    dim3(8192), dim3(256), 0, stream, pw, PWb);
  hipLaunchKernelGGL(prep_wvt_kernel,   dim3(4096), dim3(256), 0, stream, wvs, WvT);
  hipLaunchKernelGGL(fill_attns_kernel, dim3(128),  dim3(256), 0, stream, out);
  hipLaunchKernelGGL(gemm1_kernel, dim3(64, 8), dim3(256), 0, stream, v, WvT, A2);
  if (zb) {
    hipLaunchKernelGGL((gemm2_kernel<true>),  dim3(64, 32), dim3(256), 0, stream, A2, PWb, pb, zbuf);
    hipLaunchKernelGGL((ln_kernel<true>),     dim3(32768),  dim3(256), 0, stream, zbuf, v, gamma, beta, out);
  } else {
    hipLaunchKernelGGL((gemm2_kernel<false>), dim3(64, 32), dim3(256), 0, stream, A2, PWb, pb, zbuf);
    hipLaunchKernelGGL((ln_kernel<false>),    dim3(32768),  dim3(256), 0, stream, zbuf, v, gamma, beta, out);
  }
}